// Round 2
// baseline (45196.140 us; speedup 1.0000x reference)
//
#include <hip/hip_runtime.h>
#include <math.h>

#define NTH 256
#define BT  16

#define MEAN_OFF 33554432u   // 64*8192*64
#define LV_OFF   34603008u   // MEAN_OFF + 8192*128

// fast tanh for the ODE inner loop: 1 - 2/(e^{2x}+1), Newton-refined rcp.
// abs error ~1e-7; clamp keeps e^{2x} finite so the NR step never sees inf*0.
__device__ __forceinline__ float tanh_fast(float x) {
  float xx = fminf(fmaxf(x, -15.f), 15.f);
  float e  = __expf(2.f * xx);
  float d  = e + 1.f;
  float r  = __builtin_amdgcn_rcpf(d);
  r = r * (2.f - d * r);
  return fmaf(-2.f, r, 1.f);
}

// ---- staging: one 4096-float (16KB) chunk, 4 float4 per thread ----
__device__ __forceinline__ void stage_load(const float* __restrict__ g, float4 (&r)[4], int tid) {
#pragma unroll
  for (int u = 0; u < 4; ++u)
    r[u] = *(const float4*)(g + u * 1024 + tid * 4);
}
__device__ __forceinline__ void stage_store(float* __restrict__ l, const float4 (&r)[4], int tid) {
#pragma unroll
  for (int u = 0; u < 4; ++u)
    *(float4*)(l + u * 1024 + tid * 4) = r[u];
}

// ---- G1 chunk: A[16 x K] @ Wchunk[16 x 256], R=8 x C=2 contiguous ----
// thread cols {c, c+1}; rows r1..r1+7 (r1 wave-uniform -> A reads broadcast)
template<int SA>
__device__ __forceinline__ void g1_chunk(const float* __restrict__ A,
                                         const float* __restrict__ W,
                                         int c, float (&acc)[8][2]) {
#pragma unroll
  for (int j4 = 0; j4 < 4; ++j4) {
    const int kk = j4 * 4;
    float4 a[8];
#pragma unroll
    for (int i = 0; i < 8; ++i)
      a[i] = *(const float4*)(A + i * SA + kk);
    float2 w[4];
#pragma unroll
    for (int j = 0; j < 4; ++j)
      w[j] = *(const float2*)(W + (kk + j) * 256 + c);
#pragma unroll
    for (int i = 0; i < 8; ++i) {
      const float af[4] = {a[i].x, a[i].y, a[i].z, a[i].w};
#pragma unroll
      for (int j = 0; j < 4; ++j) {
        acc[i][0] = fmaf(af[j], w[j].x, acc[i][0]);
        acc[i][1] = fmaf(af[j], w[j].y, acc[i][1]);
      }
    }
  }
}

// ---- ODE G2 chunk: TMP[16 x 256] @ W2chunk[32 x 128], R=8 x C=1 ----
__device__ __forceinline__ void g2_chunk(const float* __restrict__ A,
                                         const float* __restrict__ W,
                                         int c, float (&acc)[8]) {
#pragma unroll 4
  for (int j4 = 0; j4 < 8; ++j4) {
    const int kk = j4 * 4;
    float4 a[8];
#pragma unroll
    for (int i = 0; i < 8; ++i)
      a[i] = *(const float4*)(A + i * 256 + kk);
    float w[4];
#pragma unroll
    for (int j = 0; j < 4; ++j)
      w[j] = W[(kk + j) * 128 + c];
#pragma unroll
    for (int i = 0; i < 8; ++i) {
      acc[i] = fmaf(a[i].x, w[0], acc[i]);
      acc[i] = fmaf(a[i].y, w[1], acc[i]);
      acc[i] = fmaf(a[i].z, w[2], acc[i]);
      acc[i] = fmaf(a[i].w, w[3], acc[i]);
    }
  }
}

// ---- decoder G2 chunk: TMP[16 x 256] @ Wd2chunk[64 x 64], R=4 x C=1 ----
__device__ __forceinline__ void gd2_chunk(const float* __restrict__ A,
                                          const float* __restrict__ W,
                                          int c, float (&acc)[4]) {
#pragma unroll 4
  for (int j4 = 0; j4 < 16; ++j4) {
    const int kk = j4 * 4;
    float4 a[4];
#pragma unroll
    for (int i = 0; i < 4; ++i)
      a[i] = *(const float4*)(A + i * 256 + kk);
    float w[4];
#pragma unroll
    for (int j = 0; j < 4; ++j)
      w[j] = W[(kk + j) * 64 + c];
#pragma unroll
    for (int i = 0; i < 4; ++i) {
      acc[i] = fmaf(a[i].x, w[0], acc[i]);
      acc[i] = fmaf(a[i].y, w[1], acc[i]);
      acc[i] = fmaf(a[i].z, w[2], acc[i]);
      acc[i] = fmaf(a[i].w, w[3], acc[i]);
    }
  }
}

extern "C" __global__ void __launch_bounds__(NTH, 2)
latent_ode_fused(const float* __restrict__ obs,
                 const float* __restrict__ ptimes,
                 const float* __restrict__ eps,
                 const float* __restrict__ Wi2h, const float* __restrict__ bi2h,
                 const float* __restrict__ Wh2o, const float* __restrict__ bh2o,
                 const float* __restrict__ Wode1, const float* __restrict__ bode1,
                 const float* __restrict__ Wode2, const float* __restrict__ bode2,
                 const float* __restrict__ Wdec1, const float* __restrict__ bdec1,
                 const float* __restrict__ Wdec2, const float* __restrict__ bdec2,
                 float* __restrict__ out)
{
  // 56 KB LDS carve (phase-aliased), 2 blocks/CU:
  //  [0,4096)      : encoder H[16][256] / Wh2o OUT[16][256] / ODE TMP[16][256]
  //  [4096,6144)   : encoder XS dbuf 2x[16][64]  | ODE ZC[16][128]
  //  [6144,14336)  : weight chunk double buffer, 2 x 4096 floats
  __shared__ float smem[14336];
  float* const H   = smem;
  float* const TMP = smem;
  float* const XS  = smem + 4096;
  float* const ZC  = smem + 4096;
  float* const WB0 = smem + 6144;
  float* const WB1 = smem + 10240;

  const int tid = threadIdx.x;
  const int b0  = blockIdx.x * BT;

  // G1 ownership (R8 x C2, contiguous cols; r1 wave-uniform)
  const int c1 = (tid & 127) * 2;
  const int r1 = (tid >> 7) * 8;
  // ODE G2 ownership (R8 x C1)
  const int c2 = tid & 127;
  const int r2 = (tid >> 7) * 8;
  // decoder G2 ownership (R4 x C1)
  const int cd = tid & 63;
  const int rd = (tid >> 6) * 4;

  const float2 be  = *(const float2*)(bi2h + c1);
  const float2 bm  = *(const float2*)(bh2o + c1);
  const float2 bo1 = *(const float2*)(bode1 + c1);
  const float  bo2 = bode2[c2];
  const float2 bd1 = *(const float2*)(bdec1 + c1);
  const float  bd2 = bdec2[cd];

  // zero H (initial hidden state)
#pragma unroll
  for (int u = 0; u < 4; ++u)
    *(float4*)(smem + (u * NTH + tid) * 4) = make_float4(0.f, 0.f, 0.f, 0.f);

  // prologue: XS(s=127) -> buf1, Wi2h chunk0 -> WB0
  {
    const int rr = tid >> 4, kp = (tid & 15) * 4;
    float4 x = *(const float4*)(obs + ((size_t)(b0 + rr) * 128 + 127) * 64 + kp);
    *(float4*)(XS + 1024 + rr * 64 + kp) = x;
    float4 wr[4];
    stage_load(Wi2h, wr, tid);
    stage_store(WB0, wr, tid);
  }

  float acc[8][2];
#pragma unroll
  for (int i = 0; i < 8; ++i) { acc[i][0] = be.x; acc[i][1] = be.y; }

  // ================= encoder: 128 reversed RNN steps, 20 chunks each =================
#pragma unroll 1
  for (int it = 0; it < 128; ++it) {
    const int s = 127 - it;
    const float* xs_cur = XS + (s & 1) * 1024;
    float4 xr;
#pragma unroll 1
    for (int c = 0; c < 20; ++c) {
      __syncthreads();
      if (c == 0) {
        if (it > 0) {
#pragma unroll
          for (int i = 0; i < 8; ++i)
            *(float2*)(H + (r1 + i) * 256 + c1) =
                make_float2(tanhf(acc[i][0]), tanhf(acc[i][1]));
#pragma unroll
          for (int i = 0; i < 8; ++i) { acc[i][0] = be.x; acc[i][1] = be.y; }
        }
        if (s > 0) {
          const int rr = tid >> 4, kp = (tid & 15) * 4;
          xr = *(const float4*)(obs + ((size_t)(b0 + rr) * 128 + (s - 1)) * 64 + kp);
        }
      }
      float4 wr[4];
      const float* nw = (c < 19) ? (Wi2h + (size_t)(c + 1) * 4096)
                                 : ((it < 127) ? Wi2h : Wh2o);
      stage_load(nw, wr, tid);
      const float* wc = (c & 1) ? WB1 : WB0;
      if (c < 4) g1_chunk<64>(xs_cur + r1 * 64 + 16 * c, wc, c1, acc);
      else       g1_chunk<256>(H + r1 * 256 + 16 * (c - 4), wc, c1, acc);
      stage_store((c & 1) ? WB0 : WB1, wr, tid);
      if (c == 0 && s > 0) {
        const int rr = tid >> 4, kp = (tid & 15) * 4;
        *(float4*)(XS + ((s - 1) & 1) * 1024 + rr * 64 + kp) = xr;
      }
    }
  }

  // ================= h_final -> Wh2o -> (z0_mean, z0_logvar) -> z0 =================
  __syncthreads();
#pragma unroll
  for (int i = 0; i < 8; ++i)
    *(float2*)(H + (r1 + i) * 256 + c1) =
        make_float2(tanhf(acc[i][0]), tanhf(acc[i][1]));
#pragma unroll
  for (int i = 0; i < 8; ++i) { acc[i][0] = bm.x; acc[i][1] = bm.y; }
#pragma unroll 1
  for (int c = 0; c < 16; ++c) {
    __syncthreads();
    float4 wr[4];
    const float* nw = (c < 15) ? (Wh2o + (size_t)(c + 1) * 4096) : Wdec1;
    stage_load(nw, wr, tid);
    g1_chunk<256>(H + r1 * 256 + 16 * c, (c & 1) ? WB1 : WB0, c1, acc);
    stage_store((c & 1) ? WB0 : WB1, wr, tid);
  }
  __syncthreads();   // all H reads done; overwrite H region with OUT = h@Wh2o + b
#pragma unroll
  for (int i = 0; i < 8; ++i)
    *(float2*)(H + (r1 + i) * 256 + c1) = make_float2(acc[i][0], acc[i][1]);
  __syncthreads();
  {
    const int rz = tid >> 4, cz = (tid & 15) * 8;
    const float4 m0 = *(const float4*)(H + rz * 256 + cz);
    const float4 m1 = *(const float4*)(H + rz * 256 + cz + 4);
    const float4 l0 = *(const float4*)(H + rz * 256 + 128 + cz);
    const float4 l1 = *(const float4*)(H + rz * 256 + 128 + cz + 4);
    const float4 e0 = *(const float4*)(eps + (size_t)(b0 + rz) * 128 + cz);
    const float4 e1 = *(const float4*)(eps + (size_t)(b0 + rz) * 128 + cz + 4);
    *(float4*)(out + MEAN_OFF + (size_t)(b0 + rz) * 128 + cz)     = m0;
    *(float4*)(out + MEAN_OFF + (size_t)(b0 + rz) * 128 + cz + 4) = m1;
    *(float4*)(out + LV_OFF   + (size_t)(b0 + rz) * 128 + cz)     = l0;
    *(float4*)(out + LV_OFF   + (size_t)(b0 + rz) * 128 + cz + 4) = l1;
    float4 za, zb;
    za.x = fmaf(e0.x, expf(0.5f * l0.x), m0.x);
    za.y = fmaf(e0.y, expf(0.5f * l0.y), m0.y);
    za.z = fmaf(e0.z, expf(0.5f * l0.z), m0.z);
    za.w = fmaf(e0.w, expf(0.5f * l0.w), m0.w);
    zb.x = fmaf(e1.x, expf(0.5f * l1.x), m1.x);
    zb.y = fmaf(e1.y, expf(0.5f * l1.y), m1.y);
    zb.z = fmaf(e1.z, expf(0.5f * l1.z), m1.z);
    zb.w = fmaf(e1.w, expf(0.5f * l1.w), m1.w);
    *(float4*)(ZC + rz * 128 + cz)     = za;   // ZC region != OUT region, no hazard
    *(float4*)(ZC + rz * 128 + cz + 4) = zb;
  }
  __syncthreads();

  float z[8];
#pragma unroll
  for (int i = 0; i < 8; ++i) z[i] = ZC[(r2 + i) * 128 + c2];

  // ---- f(zc) = tanh(zc @ Wode1 + b1) @ Wode2 + b2 ----
  auto feval = [&](const float* nextW, float (&f)[8]) {
    float a1[8][2];
#pragma unroll
    for (int i = 0; i < 8; ++i) { a1[i][0] = bo1.x; a1[i][1] = bo1.y; }
#pragma unroll 1
    for (int c = 0; c < 8; ++c) {
      __syncthreads();
      float4 wr[4];
      const float* nw = (c < 7) ? (Wode1 + (size_t)(c + 1) * 4096) : Wode2;
      stage_load(nw, wr, tid);
      g1_chunk<128>(ZC + r1 * 128 + 16 * c, (c & 1) ? WB1 : WB0, c1, a1);
      stage_store((c & 1) ? WB0 : WB1, wr, tid);
    }
#pragma unroll
    for (int i = 0; i < 8; ++i)
      *(float2*)(TMP + (r1 + i) * 256 + c1) =
          make_float2(tanh_fast(a1[i][0]), tanh_fast(a1[i][1]));
    float a2[8];
#pragma unroll
    for (int i = 0; i < 8; ++i) a2[i] = bo2;
#pragma unroll 1
    for (int c = 0; c < 8; ++c) {
      __syncthreads();
      float4 wr[4];
      const float* nw = (c < 7) ? (Wode2 + (size_t)(c + 1) * 4096) : nextW;
      stage_load(nw, wr, tid);
      g2_chunk(TMP + r2 * 256 + 32 * c, (c & 1) ? WB1 : WB0, c2, a2);
      stage_store((c & 1) ? WB0 : WB1, wr, tid);
    }
#pragma unroll
    for (int i = 0; i < 8; ++i) f[i] = a2[i];
  };

  // ---- decode z (in ZC) -> out[t] ----
  auto decode = [&](int t, const float* nextW) {
    float a1[8][2];
#pragma unroll
    for (int i = 0; i < 8; ++i) { a1[i][0] = bd1.x; a1[i][1] = bd1.y; }
#pragma unroll 1
    for (int c = 0; c < 8; ++c) {
      __syncthreads();
      float4 wr[4];
      const float* nw = (c < 7) ? (Wdec1 + (size_t)(c + 1) * 4096) : Wdec2;
      stage_load(nw, wr, tid);
      g1_chunk<128>(ZC + r1 * 128 + 16 * c, (c & 1) ? WB1 : WB0, c1, a1);
      stage_store((c & 1) ? WB0 : WB1, wr, tid);
    }
#pragma unroll
    for (int i = 0; i < 8; ++i)
      *(float2*)(TMP + (r1 + i) * 256 + c1) =
          make_float2(fmaxf(a1[i][0], 0.f), fmaxf(a1[i][1], 0.f));
    float a2[4];
#pragma unroll
    for (int i = 0; i < 4; ++i) a2[i] = bd2;
#pragma unroll 1
    for (int c = 0; c < 4; ++c) {
      __syncthreads();
      float4 wr[4];
      const float* nw = (c < 3) ? (Wdec2 + (size_t)(c + 1) * 4096) : nextW;
      stage_load(nw, wr, tid);
      gd2_chunk(TMP + rd * 256 + 64 * c, (c & 1) ? WB1 : WB0, cd, a2);
      stage_store((c & 1) ? WB0 : WB1, wr, tid);
    }
#pragma unroll
    for (int i = 0; i < 4; ++i)
      out[(size_t)t * 524288 + (size_t)(b0 + rd + i) * 64 + cd] = a2[i];
  };

  decode(0, Wode1);

  // ================= 63 intervals x 4 RK4 substeps =================
  float kacc[8];
#pragma unroll 1
  for (int t = 0; t < 63; ++t) {
    const float dt = (ptimes[t + 1] - ptimes[t]) * 0.25f;
#pragma unroll 1
    for (int ss = 0; ss < 4; ++ss) {
      float f[8];
      // k1
      feval(Wode1, f);
      {
        const float h = 0.5f * dt;
#pragma unroll
        for (int i = 0; i < 8; ++i) {
          kacc[i] = f[i];
          ZC[(r2 + i) * 128 + c2] = fmaf(h, f[i], z[i]);
        }
      }
      // k2
      feval(Wode1, f);
      {
        const float h = 0.5f * dt;
#pragma unroll
        for (int i = 0; i < 8; ++i) {
          kacc[i] = fmaf(2.f, f[i], kacc[i]);
          ZC[(r2 + i) * 128 + c2] = fmaf(h, f[i], z[i]);
        }
      }
      // k3
      feval(Wode1, f);
      {
#pragma unroll
        for (int i = 0; i < 8; ++i) {
          kacc[i] = fmaf(2.f, f[i], kacc[i]);
          ZC[(r2 + i) * 128 + c2] = fmaf(dt, f[i], z[i]);
        }
      }
      // k4 + state update
      feval((ss < 3) ? Wode1 : Wdec1, f);
      {
        const float h6 = dt * (1.0f / 6.0f);
#pragma unroll
        for (int i = 0; i < 8; ++i) {
          z[i] = fmaf(h6, kacc[i] + f[i], z[i]);
          ZC[(r2 + i) * 128 + c2] = z[i];
        }
      }
    }
    decode(t + 1, Wode1);
  }
}

extern "C" void kernel_launch(void* const* d_in, const int* in_sizes, int n_in,
                              void* d_out, int out_size, void* d_ws, size_t ws_size,
                              hipStream_t stream) {
  const float* obs    = (const float*)d_in[0];
  // d_in[1] = observed_times (unused by the reference)
  const float* ptimes = (const float*)d_in[2];
  const float* eps    = (const float*)d_in[3];
  const float* Wi2h   = (const float*)d_in[4];
  const float* bi2h   = (const float*)d_in[5];
  const float* Wh2o   = (const float*)d_in[6];
  const float* bh2o   = (const float*)d_in[7];
  const float* Wode1  = (const float*)d_in[8];
  const float* bode1  = (const float*)d_in[9];
  const float* Wode2  = (const float*)d_in[10];
  const float* bode2  = (const float*)d_in[11];
  const float* Wdec1  = (const float*)d_in[12];
  const float* bdec1  = (const float*)d_in[13];
  const float* Wdec2  = (const float*)d_in[14];
  const float* bdec2  = (const float*)d_in[15];

  latent_ode_fused<<<dim3(8192 / BT), dim3(NTH), 0, stream>>>(
      obs, ptimes, eps, Wi2h, bi2h, Wh2o, bh2o,
      Wode1, bode1, Wode2, bode2, Wdec1, bdec1, Wdec2, bdec2,
      (float*)d_out);
}